// Round 7
// baseline (1147.907 us; speedup 1.0000x reference)
//
#include <hip/hip_runtime.h>
#include <math.h>

// ws layout (floats):
//   esq   : [4096]                 @ 0
//   state : [2][64*8192]  ping-pong f_rest [b][yx*32+c]
//   fhat  : [64*8192]     [b][yx*32+c]
//   psc   : [2][64][8][256] float  ping-pong partial argmin scores
//   pix   : [2][64][8][256] int
#define WS_ESQ   0
#define WS_STATE 4096
#define WS_FHAT  (4096 + 2*524288)
#define WS_PSC   (4096 + 3*524288)
#define WS_PIX   (4096 + 3*524288 + 262144)

__device__ __forceinline__ float4 v4add(float4 a, float4 b) {
    return make_float4(__fadd_rn(a.x,b.x), __fadd_rn(a.y,b.y),
                       __fadd_rn(a.z,b.z), __fadd_rn(a.w,b.w));
}
__device__ __forceinline__ float4 v4sq(float4 a) {
    return make_float4(__fmul_rn(a.x,a.x), __fmul_rn(a.y,a.y),
                       __fmul_rn(a.z,a.z), __fmul_rn(a.w,a.w));
}
// numpy pairwise sum of 32 pre-rounded squares held in 8 float4s
__device__ __forceinline__ float np_pw32(float4 q0, float4 q1, float4 q2, float4 q3,
                                         float4 q4, float4 q5, float4 q6, float4 q7) {
    float4 rA = v4add(v4add(v4add(q0, q2), q4), q6);   // r[0..3]
    float4 rB = v4add(v4add(v4add(q1, q3), q5), q7);   // r[4..7]
    float l = __fadd_rn(__fadd_rn(rA.x, rA.y), __fadd_rn(rA.z, rA.w));
    float h = __fadd_rn(__fadd_rn(rB.x, rB.y), __fadd_rn(rB.z, rB.w));
    return __fadd_rn(l, h);
}
__device__ __forceinline__ float np_pw32_p(const float* zp) {
    float4 a0 = make_float4(zp[0],zp[1],zp[2],zp[3]);
    float4 a1 = make_float4(zp[4],zp[5],zp[6],zp[7]);
    float4 a2 = make_float4(zp[8],zp[9],zp[10],zp[11]);
    float4 a3 = make_float4(zp[12],zp[13],zp[14],zp[15]);
    float4 a4 = make_float4(zp[16],zp[17],zp[18],zp[19]);
    float4 a5 = make_float4(zp[20],zp[21],zp[22],zp[23]);
    float4 a6 = make_float4(zp[24],zp[25],zp[26],zp[27]);
    float4 a7 = make_float4(zp[28],zp[29],zp[30],zp[31]);
    return np_pw32(v4sq(a0),v4sq(a1),v4sq(a2),v4sq(a3),
                   v4sq(a4),v4sq(a5),v4sq(a6),v4sq(a7));
}

// break uniformity analysis: force the pointer into VGPRs so emb-row loads
// become vmcnt-pipelined vector loads (not serial s_load chains)
__device__ __forceinline__ const float* opq(const float* p) {
    asm("" : "+v"(p));
    return p;
}

__global__ void vq_prep(const float* __restrict__ emb, float* __restrict__ esq) {
    int j = blockIdx.x * 256 + threadIdx.x;
    if (j < 4096) {
        const float4* e4 = (const float4*)(emb + (size_t)j*32);
        esq[j] = np_pw32(v4sq(e4[0]),v4sq(e4[1]),v4sq(e4[2]),v4sq(e4[3]),
                         v4sq(e4[4]),v4sq(e4[5]),v4sq(e4[6]),v4sq(e4[7]));
    }
}

__device__ __forceinline__ double keys64(double x) {
    // jax keys cubic (a=-0.5)
    if (x < 1.0)      return ((1.5*x - 2.5)*x)*x + 1.0;
    else if (x < 2.0) return ((-0.5*x + 2.5)*x - 4.0)*x + 2.0;
    return 0.0;
}

#define DT(EV, ZV) \
    acc = __fmaf_rn(EV.x, ZV.x, acc); acc = __fmaf_rn(EV.y, ZV.y, acc); \
    acc = __fmaf_rn(EV.z, ZV.z, acc); acc = __fmaf_rn(EV.w, ZV.w, acc);

// Fused per-scale kernel. Grid = 64 batches x 8 code-chunks of 512.
// Phases: apply previous scale (redundant per chunk-WG; cb==0 persists),
// pool, then lean scan of this WG's 512 codes. All fp32 sequences
// bit-identical to the validated round-3/4 kernels.
__global__ __launch_bounds__(512, 4) void vq_scale(
    const float* __restrict__ f, const float* __restrict__ emb,
    const float* __restrict__ esq, float* __restrict__ state,
    float* __restrict__ fhat, float* __restrict__ psc, int* __restrict__ pix,
    int sIdx, int pn, int pnPrev)
{
    __shared__ float frest[256*33];   // [yx*33+c]
    __shared__ float zh[5600];        // union: h [v*32+c] / pooled z [v*33+c]
    __shared__ int   idx_arr[256];
    __shared__ float U[256];          // bicubic weights [out][in]
    __shared__ float zsqs[64];
    __shared__ float red_f[512];
    __shared__ int   red_i[512];

    const int tid = threadIdx.x;
    const int b   = blockIdx.x >> 3;
    const int cb  = blockIdx.x & 7;

    // ---- P1: load f_rest into LDS ----
    if (sIdx == 0) {
        for (int o = tid; o < 8192; o += 512) {            // o = c*256+yx (coalesced in f)
            int c = o >> 8, yx = o & 255;
            frest[yx*33 + c] = f[b*8192 + o];
        }
    } else {
        const float* st = state + (size_t)(sIdx & 1)*524288 + b*8192;
        for (int o = tid; o < 8192; o += 512)
            frest[(o >> 5)*33 + (o & 31)] = st[o];
    }
    __syncthreads();

    if (sIdx > 0) {
        const int Vp = pnPrev * pnPrev;
        const int ps = (sIdx - 1) & 1;
        // ---- P2: combine prev partials (ascending chunk = ascending j) ----
        if (tid < Vp) {
            float best = INFINITY; int bi = 0;
            const size_t pb0 = (((size_t)ps*64 + b)*8)*256 + tid;
            for (int ch = 0; ch < 8; ++ch) {
                float sc = psc[pb0 + ch*256];
                if (sc < best) { best = sc; bi = pix[pb0 + ch*256]; }
            }
            idx_arr[tid] = bi;
        }
        __syncthreads();
        // ---- P3: gather h = emb[idx] ----
        for (int t = tid; t < Vp*32; t += 512)
            zh[t] = emb[(size_t)idx_arr[t >> 5]*32 + (t & 31)];
        // ---- P4: bicubic weights in fp64 exactly like jax ----
        if (tid < 16) {
            double scl = 16.0 / (double)pnPrev;
            double inv = 1.0 / scl;
            double s = ((double)tid + 0.5) * inv - 0.5;
            double w64[16]; double tot = 0.0;
            for (int q = 0; q < pnPrev; ++q) {
                double wv = keys64(fabs(s - (double)q));
                w64[q] = wv; tot += wv;
            }
            for (int q = 0; q < pnPrev; ++q) U[tid*16 + q] = (float)(w64[q] / tot);
        }
        __syncthreads();
        // ---- P5: windowed bicubic apply (zero taps are exact +0.0 identities);
        //          term=fl(fl(h*wy)*wx), p outer asc, q inner asc, fl adds ----
        float* stn = state + (size_t)((sIdx + 1) & 1)*524288 + b*8192;
        float* fh  = fhat + (size_t)b*8192;
        const double inv = 1.0 / (16.0 / (double)pnPrev);
        for (int o = tid; o < 8192; o += 512) {
            int c = o & 31, yx = o >> 5, y = yx >> 4, x = yx & 15;
            double sy = ((double)y + 0.5) * inv - 0.5;
            double sx = ((double)x + 0.5) * inv - 0.5;
            int p0 = (int)floor(sy) - 1, q0 = (int)floor(sx) - 1;
            int pa = max(0, p0), pb = min(pnPrev - 1, p0 + 3);
            int qa = max(0, q0), qb = min(pnPrev - 1, q0 + 3);
            float acc = 0.f;
            for (int p = pa; p <= pb; ++p) {
                float wy = U[y*16 + p];
                for (int q = qa; q <= qb; ++q) {
                    float t0 = __fmul_rn(zh[(p*pnPrev + q)*32 + c], wy);
                    t0 = __fmul_rn(t0, U[x*16 + q]);
                    acc = __fadd_rn(acc, t0);
                }
            }
            float fr = __fsub_rn(frest[yx*33 + c], acc);
            frest[yx*33 + c] = fr;
            if (cb == 0) {
                stn[o] = fr;
                fh[o] = (sIdx == 1) ? acc : __fadd_rn(fh[o], acc);  // f_hat chain
            }
        }
        __syncthreads();
    } else {
        // s==0: persist permuted f as initial state (slot 1)
        float* stn = state + (size_t)524288 + b*8192;
        if (cb == 0)
            for (int o = tid; o < 8192; o += 512)
                stn[o] = frest[(o >> 5)*33 + (o & 31)];
    }

    // ---- P7: area pooling -> zh[v*33+c] (np einsum order), skip pn==16 ----
    const int V = pn * pn;
    if (pn < 16) {
        for (int t = tid; t < V*32; t += 512) {
            int v = t >> 5, c = t & 31;
            int p = v / pn, q = v - p*pn;
            int sh = (p*16)/pn, eh = ((p+1)*16 + pn - 1)/pn;
            int sw = (q*16)/pn, ew = ((q+1)*16 + pn - 1)/pn;
            float Mh = (float)(1.0/(double)(eh - sh));
            float Mw = (float)(1.0/(double)(ew - sw));
            float coef = __fmul_rn(Mh, Mw);
            float acc = 0.f;
            for (int hh = sh; hh < eh; ++hh)
                for (int wy = sw; wy < ew; ++wy)
                    acc = __fadd_rn(acc, __fmul_rn(coef, frest[(hh*16 + wy)*33 + c]));
            zh[v*33 + c] = acc;
        }
    }
    __syncthreads();

    const int w = tid >> 6, lane = tid & 63;
    const int cs = sIdx & 1;
    const size_t outbase = (((size_t)cs*64 + b)*8 + cb)*256;

    if (V >= 64) {
        // ---- vector mode: lane = vector, wave-uniform code (forced vector loads) ----
        const int G    = (V + 63) >> 6;       // 1,2,3,4
        const int subs = 8 / G;               // 8,4,2,2
        const int g = w / subs, sub = w - g*subs;
        const bool act = (g < G);
        float4 z0={0,0,0,0},z1={0,0,0,0},z2={0,0,0,0},z3={0,0,0,0};
        float4 z4={0,0,0,0},z5={0,0,0,0},z6={0,0,0,0},z7={0,0,0,0};
        float myzsq = 0.f;
        if (act) {
            const int vc = min(g*64 + lane, V - 1);
            const float* zp = (pn == 16) ? &frest[vc*33] : &zh[vc*33];
            z0 = make_float4(zp[0],zp[1],zp[2],zp[3]);
            z1 = make_float4(zp[4],zp[5],zp[6],zp[7]);
            z2 = make_float4(zp[8],zp[9],zp[10],zp[11]);
            z3 = make_float4(zp[12],zp[13],zp[14],zp[15]);
            z4 = make_float4(zp[16],zp[17],zp[18],zp[19]);
            z5 = make_float4(zp[20],zp[21],zp[22],zp[23]);
            z6 = make_float4(zp[24],zp[25],zp[26],zp[27]);
            z7 = make_float4(zp[28],zp[29],zp[30],zp[31]);
            myzsq = np_pw32(v4sq(z0),v4sq(z1),v4sq(z2),v4sq(z3),
                            v4sq(z4),v4sq(z5),v4sq(z6),v4sq(z7));
        }
        float best = INFINITY; int bidx = 0;
        if (act) {
            const int cc    = 512 / subs;
            const int jbase = cb*512 + sub*cc;
            const float* __restrict__ ep = emb + (size_t)jbase*32;
            const float* __restrict__ sq = esq + jbase;
            #pragma unroll 2
            for (int jj = 0; jj < cc; ++jj) {
                const float* e = opq(ep + (size_t)jj*32);
                float4 e0 = *(const float4*)(e);
                float4 e1 = *(const float4*)(e + 4);
                float4 e2 = *(const float4*)(e + 8);
                float4 e3 = *(const float4*)(e + 12);
                float4 e4 = *(const float4*)(e + 16);
                float4 e5 = *(const float4*)(e + 20);
                float4 e6 = *(const float4*)(e + 24);
                float4 e7 = *(const float4*)(e + 28);
                float acc = 0.f;
                DT(e0, z0) DT(e1, z1) DT(e2, z2) DT(e3, z3)
                DT(e4, z4) DT(e5, z5) DT(e6, z6) DT(e7, z7)
                float d = __fsub_rn(__fadd_rn(myzsq, sq[jj]), __fmul_rn(2.0f, acc));
                if (d < best) { best = d; bidx = jbase + jj; }  // strict <: first-index
            }
        }
        red_f[w*64 + lane] = best;
        red_i[w*64 + lane] = bidx;
        __syncthreads();
        if (tid < V) {
            int gg = tid >> 6, ll = tid & 63;
            float bb = INFINITY; int bi = 0;
            for (int s2 = 0; s2 < subs; ++s2) {     // ascending sub = ascending j
                float sc = red_f[(gg*subs + s2)*64 + ll];
                if (sc < bb) { bb = sc; bi = red_i[(gg*subs + s2)*64 + ll]; }
            }
            psc[outbase + tid] = bb;
            pix[outbase + tid] = bi;
        }
    } else {
        // ---- code-parallel mode: lane = code, z broadcast from LDS ----
        if (tid < V) zsqs[tid] = np_pw32_p(&zh[tid*33]);
        __syncthreads();
        const int j = cb*512 + w*64 + lane;
        const float* e = emb + (size_t)j*32;     // lane-varying: natural vector loads
        float4 e0 = *(const float4*)(e);
        float4 e1 = *(const float4*)(e + 4);
        float4 e2 = *(const float4*)(e + 8);
        float4 e3 = *(const float4*)(e + 12);
        float4 e4 = *(const float4*)(e + 16);
        float4 e5 = *(const float4*)(e + 20);
        float4 e6 = *(const float4*)(e + 24);
        float4 e7 = *(const float4*)(e + 28);
        const float esqj = esq[j];
        for (int v = 0; v < V; ++v) {
            const float* zp = &zh[v*33];
            float4 z0 = make_float4(zp[0],zp[1],zp[2],zp[3]);
            float4 z1 = make_float4(zp[4],zp[5],zp[6],zp[7]);
            float4 z2 = make_float4(zp[8],zp[9],zp[10],zp[11]);
            float4 z3 = make_float4(zp[12],zp[13],zp[14],zp[15]);
            float4 z4 = make_float4(zp[16],zp[17],zp[18],zp[19]);
            float4 z5 = make_float4(zp[20],zp[21],zp[22],zp[23]);
            float4 z6 = make_float4(zp[24],zp[25],zp[26],zp[27]);
            float4 z7 = make_float4(zp[28],zp[29],zp[30],zp[31]);
            float acc = 0.f;
            DT(e0, z0) DT(e1, z1) DT(e2, z2) DT(e3, z3)
            DT(e4, z4) DT(e5, z5) DT(e6, z6) DT(e7, z7)
            float bd = __fsub_rn(__fadd_rn(zsqs[v], esqj), __fmul_rn(2.0f, acc));
            int bj = j;
            // lexicographic (d, j) butterfly = numpy first-index argmin over 64 codes
            #pragma unroll
            for (int off = 1; off < 64; off <<= 1) {
                float od = __shfl_xor(bd, off, 64);
                int   oj = __shfl_xor(bj, off, 64);
                if (od < bd || (od == bd && oj < bj)) { bd = od; bj = oj; }
            }
            if (lane == 0) { red_f[w*64 + v] = bd; red_i[w*64 + v] = bj; }
        }
        __syncthreads();
        if (tid < V) {
            float bb = INFINITY; int bi = 0;
            for (int ww = 0; ww < 8; ++ww) {        // ascending wave = ascending j
                float sc = red_f[ww*64 + tid];
                if (sc < bb) { bb = sc; bi = red_i[ww*64 + tid]; }
            }
            psc[outbase + tid] = bb;
            pix[outbase + tid] = bi;
        }
    }
}

__global__ __launch_bounds__(256) void vq_final(
    const float* __restrict__ emb, const float* __restrict__ fhat,
    const float* __restrict__ psc, const int* __restrict__ pix,
    float* __restrict__ out)
{
    __shared__ int idx_arr[256];
    const int tid = threadIdx.x;
    const int b = blockIdx.x;
    {   // combine last scale (slot 9&1 = 1) partials over 8 chunks
        float best = INFINITY; int bi = 0;
        const size_t pb0 = (((size_t)1*64 + b)*8)*256 + tid;
        for (int ch = 0; ch < 8; ++ch) {
            float sc = psc[pb0 + ch*256];
            if (sc < best) { best = sc; bi = pix[pb0 + ch*256]; }
        }
        idx_arr[tid] = bi;
    }
    __syncthreads();
    // out = transpose(f_hat + h9), BCHW coalesced (last scale: no resize)
    for (int o = tid; o < 8192; o += 256) {
        int c = o >> 8, yx = o & 255;
        out[b*8192 + o] = __fadd_rn(fhat[(size_t)b*8192 + yx*32 + c],
                                    emb[(size_t)idx_arr[yx]*32 + c]);
    }
}

extern "C" void kernel_launch(void* const* d_in, const int* in_sizes, int n_in,
                              void* d_out, int out_size, void* d_ws, size_t ws_size,
                              hipStream_t stream) {
    const float* f   = (const float*)d_in[0];
    const float* emb = (const float*)d_in[1];
    float* ws  = (float*)d_ws;
    float* out = (float*)d_out;
    float* esq   = ws + WS_ESQ;
    float* state = ws + WS_STATE;
    float* fhatp = ws + WS_FHAT;
    float* psc   = ws + WS_PSC;
    int*   pixp  = (int*)(ws + WS_PIX);
    static const int pns[10] = {1, 2, 3, 4, 5, 6, 8, 10, 13, 16};

    vq_prep<<<16, 256, 0, stream>>>(emb, esq);
    for (int s = 0; s < 10; ++s)
        vq_scale<<<512, 512, 0, stream>>>(f, emb, esq, state, fhatp, psc, pixp,
                                          s, pns[s], s > 0 ? pns[s-1] : 0);
    vq_final<<<64, 256, 0, stream>>>(emb, fhatp, psc, pixp, out);
}

// Round 8
// 1115.027 us; speedup vs baseline: 1.0295x; 1.0295x over previous
//
#include <hip/hip_runtime.h>
#include <math.h>

#define NWG 768

// ws layout (floats):
//   esq  : [4096]            @ 0
//   fhat : [64*8192]         @ 4096                 [b][yx*32+c]
//   z    : [16384*32]        @ 4096+524288          pair=(v<<6|b) rows
//   psc  : [131072]          @ 4096+2*524288        pair*NCB+cb (per-scale NCB)
//   pix  : [131072] int      @ ... + 131072
//   bar  : [80] uint         @ ... + 131072         cnt[64] + gen
#define WS_ESQ   0
#define WS_FHAT  4096
#define WS_Z     (4096 + 524288)
#define WS_PSC   (4096 + 524288 + 524288)
#define WS_PIX   (WS_PSC + 131072)
#define WS_BAR   (WS_PIX + 131072)

__constant__ int c_pn[10]  = {1, 2, 3, 4, 5, 6, 8, 10, 13, 16};
__constant__ int c_ncb[10] = {64, 64, 64, 64, 59, 42, 24, 15, 9, 6};
__constant__ int c_cb[10]  = {64, 64, 64, 64, 70, 98, 171, 274, 456, 683};

__device__ __forceinline__ float4 v4add(float4 a, float4 b) {
    return make_float4(__fadd_rn(a.x,b.x), __fadd_rn(a.y,b.y),
                       __fadd_rn(a.z,b.z), __fadd_rn(a.w,b.w));
}
__device__ __forceinline__ float4 v4sq(float4 a) {
    return make_float4(__fmul_rn(a.x,a.x), __fmul_rn(a.y,a.y),
                       __fmul_rn(a.z,a.z), __fmul_rn(a.w,a.w));
}
// numpy pairwise sum of 32 pre-rounded squares held in 8 float4s
__device__ __forceinline__ float np_pw32(float4 q0, float4 q1, float4 q2, float4 q3,
                                         float4 q4, float4 q5, float4 q6, float4 q7) {
    float4 rA = v4add(v4add(v4add(q0, q2), q4), q6);   // r[0..3]
    float4 rB = v4add(v4add(v4add(q1, q3), q5), q7);   // r[4..7]
    float l = __fadd_rn(__fadd_rn(rA.x, rA.y), __fadd_rn(rA.z, rA.w));
    float h = __fadd_rn(__fadd_rn(rB.x, rB.y), __fadd_rn(rB.z, rB.w));
    return __fadd_rn(l, h);
}

__device__ __forceinline__ double keys64(double x) {
    // jax keys cubic (a=-0.5)
    if (x < 1.0)      return ((1.5*x - 2.5)*x)*x + 1.0;
    else if (x < 2.0) return ((-0.5*x + 2.5)*x - 4.0)*x + 2.0;
    return 0.0;
}

// ---- device-wide barrier: 32-way split counters + generation word ----
// All data writes drained by __syncthreads (vmcnt) + leader __threadfence
// (agent release: L2 writeback). Waiters: relaxed spin + trailing
// __threadfence (agent acquire: L1/L2 inv) -> fresh reads after barrier.
__device__ __forceinline__ void gbar(unsigned* bar, int epoch, int wg) {
    __syncthreads();
    if (threadIdx.x == 0) {
        unsigned* cnt  = bar + ((epoch & 1) << 5);
        unsigned* genp = bar + 64;
        __threadfence();
        __hip_atomic_fetch_add(&cnt[wg & 31], 1u, __ATOMIC_RELAXED,
                               __HIP_MEMORY_SCOPE_AGENT);
        if (wg == 0) {
            for (long it = 0; it < (1L << 22); ++it) {
                unsigned s = 0;
                #pragma unroll
                for (int i = 0; i < 32; ++i)
                    s += __hip_atomic_load(&cnt[i], __ATOMIC_RELAXED,
                                           __HIP_MEMORY_SCOPE_AGENT);
                if (s == (unsigned)NWG) break;
                __builtin_amdgcn_s_sleep(2);
            }
            #pragma unroll
            for (int i = 0; i < 32; ++i)   // reset for epoch+2 (safe: precedes gen bump)
                __hip_atomic_store(&cnt[i], 0u, __ATOMIC_RELAXED,
                                   __HIP_MEMORY_SCOPE_AGENT);
            __threadfence();
            __hip_atomic_store(genp, (unsigned)(epoch + 1), __ATOMIC_RELEASE,
                               __HIP_MEMORY_SCOPE_AGENT);
        } else {
            for (long it = 0; it < (1L << 22); ++it) {
                if (__hip_atomic_load(genp, __ATOMIC_RELAXED,
                                      __HIP_MEMORY_SCOPE_AGENT) >= (unsigned)(epoch + 1))
                    break;
                __builtin_amdgcn_s_sleep(2);
            }
            __threadfence();
        }
    }
    __syncthreads();
}

__global__ void vq_init(const float* __restrict__ emb, float* __restrict__ esq,
                        unsigned* __restrict__ bar) {
    if (blockIdx.x < 16) {
        int j = blockIdx.x * 256 + threadIdx.x;
        const float4* e4 = (const float4*)(emb + (size_t)j*32);
        esq[j] = np_pw32(v4sq(e4[0]),v4sq(e4[1]),v4sq(e4[2]),v4sq(e4[3]),
                         v4sq(e4[4]),v4sq(e4[5]),v4sq(e4[6]),v4sq(e4[7]));
    } else {
        if (threadIdx.x < 80) bar[threadIdx.x] = 0u;
    }
}

#define DOT4P(E, OFF, ZA, ZB) \
    acc0 = __fmaf_rn(E[OFF+0], ZA.x, acc0); acc1 = __fmaf_rn(E[OFF+0], ZB.x, acc1); \
    acc0 = __fmaf_rn(E[OFF+1], ZA.y, acc0); acc1 = __fmaf_rn(E[OFF+1], ZB.y, acc1); \
    acc0 = __fmaf_rn(E[OFF+2], ZA.z, acc0); acc1 = __fmaf_rn(E[OFF+2], ZB.z, acc1); \
    acc0 = __fmaf_rn(E[OFF+3], ZA.w, acc0); acc1 = __fmaf_rn(E[OFF+3], ZB.w, acc1);

// Persistent kernel: 768 WGs x 256 threads = 3 WGs/CU (co-resident by
// resource fit: VGPR capped by launch_bounds, LDS 20.8KB, 12 waves/CU).
// WGs 0..255 = owners (batch b = wg>>2, channels cg*8..cg*8+8) keep f_rest
// resident in LDS across all 10 scales. Scans partition (pairblocks x NCB
// code-chunks) over all 768 WGs with the round-6 s_load inner loop.
__global__ __launch_bounds__(256, 3) void vq_run(
    const float* __restrict__ f, const float* __restrict__ emb,
    const float* __restrict__ esq, float* __restrict__ fhat,
    float* __restrict__ zws, float* __restrict__ psc, int* __restrict__ pix,
    unsigned* __restrict__ bar, float* __restrict__ out)
{
    __shared__ float fr[2304];     // f_rest slice [yx*9+cc] (pad 9), persistent
    __shared__ float hs[1352];     // h slice [v*8+cc]
    __shared__ int   idx_arr[256];
    __shared__ float U[256];       // bicubic weights [out][in]
    __shared__ float red_f[512];
    __shared__ int   red_i[512];

    const int tid = threadIdx.x;
    const int wg  = blockIdx.x;
    const int b   = wg >> 2;       // owner batch (valid when wg < 256)
    const int cg  = wg & 3;
    const int c0  = cg * 8;
    int epoch = 0;

    // ---- owners: load f slice (BCHW, coalesced) into resident LDS ----
    if (wg < 256) {
        for (int o = tid; o < 2048; o += 256) {
            int cc = o >> 8, yx = o & 255;
            fr[yx*9 + cc] = f[b*8192 + (c0 + cc)*256 + yx];
        }
    }
    __syncthreads();

    for (int s = 0; s < 10; ++s) {
        const int pn = c_pn[s];
        const int V  = pn * pn;

        // ==== apply previous scale (owners only) ====
        if (s > 0 && wg < 256) {
            const int pnP = c_pn[s-1], Vp = pnP*pnP, ncbP = c_ncb[s-1];
            // P2: combine prev partials (ascending cb = ascending j)
            if (tid < Vp) {
                float best = INFINITY; int bi = 0;
                const size_t pb0 = (size_t)((tid << 6) + b) * ncbP;
                for (int ch = 0; ch < ncbP; ++ch) {
                    float sc = psc[pb0 + ch];
                    if (sc < best) { best = sc; bi = pix[pb0 + ch]; }
                }
                idx_arr[tid] = bi;
            }
            __syncthreads();
            // P3: gather h slice
            for (int t = tid; t < Vp*8; t += 256)
                hs[t] = emb[(size_t)idx_arr[t >> 3]*32 + c0 + (t & 7)];
            // P4: bicubic weights in fp64 exactly like jax
            if (tid < 16) {
                double scl = 16.0 / (double)pnP;
                double inv = 1.0 / scl;
                double sp = ((double)tid + 0.5) * inv - 0.5;
                double w64[16]; double tot = 0.0;
                for (int q = 0; q < pnP; ++q) {
                    double wv = keys64(fabs(sp - (double)q));
                    w64[q] = wv; tot += wv;
                }
                for (int q = 0; q < pnP; ++q) U[tid*16 + q] = (float)(w64[q] / tot);
            }
            __syncthreads();
            // P5: windowed bicubic apply (zero taps exact +0.0 identities);
            //     term=fl(fl(h*wy)*wx), p outer asc, q inner asc, fl adds
            const double inv = 1.0 / (16.0 / (double)pnP);
            float* fh = fhat + (size_t)b*8192;
            for (int o = tid; o < 2048; o += 256) {
                int yx = o >> 3, cc = o & 7, y = yx >> 4, x = yx & 15;
                double sy = ((double)y + 0.5) * inv - 0.5;
                double sx = ((double)x + 0.5) * inv - 0.5;
                int p0 = (int)floor(sy) - 1, q0 = (int)floor(sx) - 1;
                int pa = max(0, p0), pb = min(pnP - 1, p0 + 3);
                int qa = max(0, q0), qb = min(pnP - 1, q0 + 3);
                float acc = 0.f;
                for (int p = pa; p <= pb; ++p) {
                    float wy = U[y*16 + p];
                    for (int q = qa; q <= qb; ++q) {
                        float t0 = __fmul_rn(hs[(p*pnP + q)*8 + cc], wy);
                        t0 = __fmul_rn(t0, U[x*16 + q]);
                        acc = __fadd_rn(acc, t0);
                    }
                }
                float frv = __fsub_rn(fr[yx*9 + cc], acc);
                fr[yx*9 + cc] = frv;
                int go = yx*32 + c0 + cc;
                fh[go] = (s == 1) ? acc : __fadd_rn(fh[go], acc);   // f_hat chain
            }
            __syncthreads();
        }

        // ==== pool + z write (owners) ====
        if (wg < 256) {
            if (pn < 16) {
                for (int t = tid; t < V*8; t += 256) {
                    int v = t >> 3, cc = t & 7;
                    int p = v / pn, q = v - p*pn;
                    int sh = (p*16)/pn, eh = ((p+1)*16 + pn - 1)/pn;
                    int sw = (q*16)/pn, ew = ((q+1)*16 + pn - 1)/pn;
                    float Mh = (float)(1.0/(double)(eh - sh));
                    float Mw = (float)(1.0/(double)(ew - sw));
                    float coef = __fmul_rn(Mh, Mw);
                    float acc = 0.f;
                    for (int hh = sh; hh < eh; ++hh)
                        for (int wy = sw; wy < ew; ++wy)
                            acc = __fadd_rn(acc, __fmul_rn(coef, fr[(hh*16 + wy)*9 + cc]));
                    zws[(size_t)((v << 6) + b)*32 + c0 + cc] = acc;
                }
            } else {
                for (int o = tid; o < 2048; o += 256) {
                    int yx = o >> 3, cc = o & 7;
                    zws[(size_t)((yx << 6) + b)*32 + c0 + cc] = fr[yx*9 + cc];
                }
            }
        }
        gbar(bar, epoch++, wg);

        // ==== scan (round-6 inner loop, variable chunking) ====
        const int NCB = c_ncb[s], CB = c_cb[s];
        const int N   = V << 6;
        const int PB  = (N + 127) >> 7;
        if (wg < PB * NCB) {
            const int pblk = wg / NCB, cb = wg - pblk*NCB;
            const int w = tid >> 6, lane = tid & 63;
            const int pair0 = (pblk << 7) + lane;
            const int p0c = min(pair0, N - 1), p1c = min(pair0 + 64, N - 1);
            const float4* za = (const float4*)(zws + (size_t)p0c*32);
            const float4* zb = (const float4*)(zws + (size_t)p1c*32);
            float4 a0 = za[0], a1 = za[1], a2 = za[2], a3 = za[3];
            float4 a4 = za[4], a5 = za[5], a6 = za[6], a7 = za[7];
            float4 b0 = zb[0], b1 = zb[1], b2 = zb[2], b3 = zb[3];
            float4 b4 = zb[4], b5 = zb[5], b6 = zb[6], b7 = zb[7];
            float zsq0 = np_pw32(v4sq(a0),v4sq(a1),v4sq(a2),v4sq(a3),
                                 v4sq(a4),v4sq(a5),v4sq(a6),v4sq(a7));
            float zsq1 = np_pw32(v4sq(b0),v4sq(b1),v4sq(b2),v4sq(b3),
                                 v4sq(b4),v4sq(b5),v4sq(b6),v4sq(b7));

            const int jlo = cb * CB;
            const int CBr = min(CB, 4096 - jlo);
            const int wc  = (CBr + 3) >> 2;
            const int jb  = jlo + w*wc;
            const int count = min(wc, CBr - w*wc);
            const int jbase = __builtin_amdgcn_readfirstlane(jb);
            const float* __restrict__ ep = emb + (size_t)jbase*32;
            const float* __restrict__ sq = esq + jbase;
            float best0 = INFINITY, best1 = INFINITY; int bi0 = 0, bi1 = 0;
            #pragma unroll 2
            for (int jj = 0; jj < count; ++jj) {
                const float* e = ep + jj*32;
                float acc0 = 0.f, acc1 = 0.f;
                DOT4P(e, 0,  a0, b0) DOT4P(e, 4,  a1, b1) DOT4P(e, 8,  a2, b2) DOT4P(e, 12, a3, b3)
                DOT4P(e, 16, a4, b4) DOT4P(e, 20, a5, b5) DOT4P(e, 24, a6, b6) DOT4P(e, 28, a7, b7)
                float sqj = sq[jj];
                float d0 = __fsub_rn(__fadd_rn(zsq0, sqj), __fmul_rn(2.0f, acc0));
                float d1 = __fsub_rn(__fadd_rn(zsq1, sqj), __fmul_rn(2.0f, acc1));
                int j = jbase + jj;
                if (d0 < best0) { best0 = d0; bi0 = j; }   // strict <: first-index ties
                if (d1 < best1) { best1 = d1; bi1 = j; }
            }
            red_f[w*128 + lane]      = best0;  red_i[w*128 + lane]      = bi0;
            red_f[w*128 + 64 + lane] = best1;  red_i[w*128 + 64 + lane] = bi1;
            __syncthreads();
            if (tid < 128) {
                int p = (pblk << 7) + tid;
                if (p < N) {
                    float bb = INFINITY; int bi = 0;
                    #pragma unroll
                    for (int ww = 0; ww < 4; ++ww) {   // ascending wave = ascending j
                        float sc = red_f[ww*128 + tid];
                        if (sc < bb) { bb = sc; bi = red_i[ww*128 + tid]; }
                    }
                    psc[(size_t)p*NCB + cb] = bb;
                    pix[(size_t)p*NCB + cb] = bi;
                }
            }
        }
        gbar(bar, epoch++, wg);
    }

    // ==== epilogue (owners): combine scale-9 partials, out = fhat + h9 ====
    if (wg < 256) {
        {
            float best = INFINITY; int bi = 0;
            const size_t pb0 = (size_t)((tid << 6) + b) * 6;   // NCB(s9) = 6
            for (int ch = 0; ch < 6; ++ch) {
                float sc = psc[pb0 + ch];
                if (sc < best) { best = sc; bi = pix[pb0 + ch]; }
            }
            idx_arr[tid] = bi;
        }
        __syncthreads();
        for (int o = tid; o < 2048; o += 256) {
            int cc = o >> 8, yx = o & 255;
            int c = c0 + cc;
            out[b*8192 + c*256 + yx] = __fadd_rn(fhat[(size_t)b*8192 + yx*32 + c],
                                                 emb[(size_t)idx_arr[yx]*32 + c]);
        }
    }
}

extern "C" void kernel_launch(void* const* d_in, const int* in_sizes, int n_in,
                              void* d_out, int out_size, void* d_ws, size_t ws_size,
                              hipStream_t stream) {
    const float* f   = (const float*)d_in[0];
    const float* emb = (const float*)d_in[1];
    float* ws  = (float*)d_ws;
    float* out = (float*)d_out;
    float*    esq   = ws + WS_ESQ;
    float*    fhatp = ws + WS_FHAT;
    float*    zws   = ws + WS_Z;
    float*    psc   = ws + WS_PSC;
    int*      pixp  = (int*)(ws + WS_PIX);
    unsigned* bar   = (unsigned*)(ws + WS_BAR);

    vq_init<<<17, 256, 0, stream>>>(emb, esq, bar);
    vq_run<<<NWG, 256, 0, stream>>>(f, emb, esq, fhatp, zws, psc, pixp, bar, out);
}

// Round 9
// 432.497 us; speedup vs baseline: 2.6541x; 2.5781x over previous
//
#include <hip/hip_runtime.h>
#include <math.h>

// ws layout (floats):
//   esq   : [4096]
//   state : [64*8192]   f_rest, channel-major [b][c][yx]  (== f layout)
//   fhat  : [64*8192]   [b][c][yx]
//   z     : [16384][32] pair=(v<<6|b) rows
//   psc   : [131072]    pair*NCB+cb
//   pix   : [131072] int
#define WS_ESQ   0
#define WS_STATE 4096
#define WS_FHAT  (4096 + 524288)
#define WS_Z     (4096 + 2*524288)
#define WS_PSC   (4096 + 3*524288)
#define WS_PIX   (4096 + 3*524288 + 131072)

__device__ __forceinline__ float4 v4add(float4 a, float4 b) {
    return make_float4(__fadd_rn(a.x,b.x), __fadd_rn(a.y,b.y),
                       __fadd_rn(a.z,b.z), __fadd_rn(a.w,b.w));
}
__device__ __forceinline__ float4 v4sq(float4 a) {
    return make_float4(__fmul_rn(a.x,a.x), __fmul_rn(a.y,a.y),
                       __fmul_rn(a.z,a.z), __fmul_rn(a.w,a.w));
}
// numpy pairwise sum of 32 pre-rounded squares held in 8 float4s
__device__ __forceinline__ float np_pw32(float4 q0, float4 q1, float4 q2, float4 q3,
                                         float4 q4, float4 q5, float4 q6, float4 q7) {
    float4 rA = v4add(v4add(v4add(q0, q2), q4), q6);   // r[0..3]
    float4 rB = v4add(v4add(v4add(q1, q3), q5), q7);   // r[4..7]
    float l = __fadd_rn(__fadd_rn(rA.x, rA.y), __fadd_rn(rA.z, rA.w));
    float h = __fadd_rn(__fadd_rn(rB.x, rB.y), __fadd_rn(rB.z, rB.w));
    return __fadd_rn(l, h);
}

__device__ __forceinline__ double keys64(double x) {
    // jax keys cubic (a=-0.5)
    if (x < 1.0)      return ((1.5*x - 2.5)*x)*x + 1.0;
    else if (x < 2.0) return ((-0.5*x + 2.5)*x - 4.0)*x + 2.0;
    return 0.0;
}

// Apply kernel: 512 WGs = 64 b x 8 channel-slices of 4 (+16 esq WGs at s0).
// Combine prev partial argmins (2-stage, contiguous-ascending = first-index),
// gather h slice, bicubic-apply, persist state/fhat (channel-major), pool,
// write z rows. All fp32 sequences bit-identical to validated round-6 kernel.
__global__ __launch_bounds__(256) void vq_apply(
    const float* __restrict__ f, const float* __restrict__ emb,
    float* __restrict__ esq, float* __restrict__ state, float* __restrict__ fhat,
    float* __restrict__ zws, const float* __restrict__ psc, const int* __restrict__ pix,
    int sIdx, int pn, int pnPrev, int ncbPrev)
{
    __shared__ float fr[1280];      // f_rest slice [yx*5+cc]
    __shared__ float hs[676];       // h slice [v*4+cc]
    __shared__ int   idx_arr[176];
    __shared__ float U[256];        // bicubic weights [out][in], fp64->fp32 like jax
    __shared__ float red_f[1360];
    __shared__ int   red_i[1360];

    const int tid = threadIdx.x;
    const int wg  = blockIdx.x;
    if (wg >= 512) {                // s0 only: esq WGs
        int j = ((wg - 512) << 8) + tid;
        const float4* e4 = (const float4*)(emb + (size_t)j*32);
        esq[j] = np_pw32(v4sq(e4[0]),v4sq(e4[1]),v4sq(e4[2]),v4sq(e4[3]),
                         v4sq(e4[4]),v4sq(e4[5]),v4sq(e4[6]),v4sq(e4[7]));
        return;
    }
    const int b  = wg >> 3;
    const int c0 = (wg & 7) * 4;

    // ---- P1: load f_rest slice (channel-major, coalesced) ----
    const float* src = (sIdx <= 1) ? f : state;      // s0 never writes state: same layout
    for (int o = tid; o < 1024; o += 256) {
        int cc = o >> 8, yx = o & 255;
        fr[yx*5 + cc] = src[b*8192 + (c0 + cc)*256 + yx];
    }
    __syncthreads();

    if (sIdx > 0) {
        const int Vp = pnPrev * pnPrev;
        // ---- P2: combine prev partials, 2-stage (both contiguous ascending j) ----
        const int step = ncbPrev >> 3;
        for (int t = tid; t < Vp*8; t += 256) {
            int v = t >> 3, k = t & 7;
            const size_t base = (size_t)((v << 6) + b) * ncbPrev;
            float best = INFINITY; int bi = 0;
            for (int ch = k*step; ch < (k+1)*step; ++ch) {
                float sc = psc[base + ch];
                if (sc < best) { best = sc; bi = pix[base + ch]; }
            }
            red_f[t] = best; red_i[t] = bi;
        }
        __syncthreads();
        if (tid < Vp) {
            float best = INFINITY; int bi = 0;
            for (int k = 0; k < 8; ++k) {
                float sc = red_f[tid*8 + k];
                if (sc < best) { best = sc; bi = red_i[tid*8 + k]; }
            }
            idx_arr[tid] = bi;
        }
        __syncthreads();
        // ---- P3: gather h slice ----
        for (int t = tid; t < Vp*4; t += 256)
            hs[t] = emb[(size_t)idx_arr[t >> 2]*32 + c0 + (t & 3)];
        // ---- P4: bicubic weights in fp64 exactly like jax ----
        if (tid < 16) {
            double scl = 16.0 / (double)pnPrev;
            double inv = 1.0 / scl;
            double sp = ((double)tid + 0.5) * inv - 0.5;
            double w64[16]; double tot = 0.0;
            for (int q = 0; q < pnPrev; ++q) {
                double wv = keys64(fabs(sp - (double)q));
                w64[q] = wv; tot += wv;
            }
            for (int q = 0; q < pnPrev; ++q) U[tid*16 + q] = (float)(w64[q] / tot);
        }
        __syncthreads();
        // ---- P5: windowed bicubic apply, 1 thread per yx, 4 channels.
        //     term=fl(fl(h*wy)*wx), p outer asc, q inner asc, fl adds;
        //     zero taps outside window are exact +0.0 identities. ----
        {
            const double inv = 1.0 / (16.0 / (double)pnPrev);
            const int yx = tid, y = yx >> 4, x = yx & 15;
            double sy = ((double)y + 0.5) * inv - 0.5;
            double sx = ((double)x + 0.5) * inv - 0.5;
            int p0 = (int)floor(sy) - 1, q0 = (int)floor(sx) - 1;
            int pa = max(0, p0), pb = min(pnPrev - 1, p0 + 3);
            int qa = max(0, q0), qb = min(pnPrev - 1, q0 + 3);
            float acc0 = 0.f, acc1 = 0.f, acc2 = 0.f, acc3 = 0.f;
            for (int p = pa; p <= pb; ++p) {
                float wy = U[y*16 + p];
                for (int q = qa; q <= qb; ++q) {
                    float wx = U[x*16 + q];
                    const float* hp = &hs[(p*pnPrev + q)*4];
                    acc0 = __fadd_rn(acc0, __fmul_rn(__fmul_rn(hp[0], wy), wx));
                    acc1 = __fadd_rn(acc1, __fmul_rn(__fmul_rn(hp[1], wy), wx));
                    acc2 = __fadd_rn(acc2, __fmul_rn(__fmul_rn(hp[2], wy), wx));
                    acc3 = __fadd_rn(acc3, __fmul_rn(__fmul_rn(hp[3], wy), wx));
                }
            }
            float a4[4] = {acc0, acc1, acc2, acc3};
            #pragma unroll
            for (int cc = 0; cc < 4; ++cc) {
                float frv = __fsub_rn(fr[yx*5 + cc], a4[cc]);
                fr[yx*5 + cc] = frv;
                int go = b*8192 + (c0 + cc)*256 + yx;
                state[go] = frv;
                fhat[go] = (sIdx == 1) ? a4[cc] : __fadd_rn(fhat[go], a4[cc]);
            }
        }
        __syncthreads();
    }

    // ---- P7: area pool (np einsum order: fl(coef*f), h outer, w inner) + z write ----
    const int V = pn * pn;
    if (pn < 16) {
        if (tid < V) {
            int p = tid / pn, q = tid - p*pn;
            int sh = (p*16)/pn, eh = ((p+1)*16 + pn - 1)/pn;
            int sw = (q*16)/pn, ew = ((q+1)*16 + pn - 1)/pn;
            float Mh = (float)(1.0/(double)(eh - sh));
            float Mw = (float)(1.0/(double)(ew - sw));
            float coef = __fmul_rn(Mh, Mw);
            float a4[4] = {0.f, 0.f, 0.f, 0.f};
            for (int hh = sh; hh < eh; ++hh)
                for (int wy = sw; wy < ew; ++wy) {
                    const float* fp = &fr[(hh*16 + wy)*5];
                    #pragma unroll
                    for (int cc = 0; cc < 4; ++cc)
                        a4[cc] = __fadd_rn(a4[cc], __fmul_rn(coef, fp[cc]));
                }
            *(float4*)(zws + (size_t)((tid << 6) + b)*32 + c0) =
                make_float4(a4[0], a4[1], a4[2], a4[3]);
        }
    } else {
        const int yx = tid;
        *(float4*)(zws + (size_t)((yx << 6) + b)*32 + c0) =
            make_float4(fr[yx*5], fr[yx*5 + 1], fr[yx*5 + 2], fr[yx*5 + 3]);
    }
}

#define DOT4P(EP, K, ZA, ZB) { float4 ev = EP[K]; \
    acc0 = __fmaf_rn(ev.x, ZA.x, acc0); acc1 = __fmaf_rn(ev.x, ZB.x, acc1); \
    acc0 = __fmaf_rn(ev.y, ZA.y, acc0); acc1 = __fmaf_rn(ev.y, ZB.y, acc1); \
    acc0 = __fmaf_rn(ev.z, ZA.z, acc0); acc1 = __fmaf_rn(ev.z, ZB.z, acc1); \
    acc0 = __fmaf_rn(ev.w, ZA.w, acc0); acc1 = __fmaf_rn(ev.w, ZB.w, acc1); }

// Scan: grid = pairblocks(128 pairs) x NCB chunks. emb staged through
// double-buffered LDS tiles (coalesced float4 loads; broadcast ds_reads in
// the dot loop). Waves split codes within each tile: per-wave j strictly
// ascending; cross-wave reduce is lexicographic (d,j) == numpy first-index.
__global__ __launch_bounds__(256, 4) void vq_scan(
    const float* __restrict__ emb, const float* __restrict__ esq,
    const float* __restrict__ zws, float* __restrict__ psc, int* __restrict__ pix,
    int V, int ncbMask, int ncbShift, int CB)
{
    __shared__ float ebuf[2][2048];   // up to 64 codes x 32
    __shared__ float esq_l[512];
    __shared__ float red_f[512];
    __shared__ int   red_i[512];

    const int tid  = threadIdx.x;
    const int cb   = blockIdx.x & ncbMask;
    const int pblk = blockIdx.x >> ncbShift;
    const int w    = tid >> 6, lane = tid & 63;
    const int N    = V << 6;

    const int pair0 = (pblk << 7) + lane;
    const int p0c = min(pair0, N - 1), p1c = min(pair0 + 64, N - 1);
    const float4* za = (const float4*)(zws + (size_t)p0c*32);
    const float4* zb = (const float4*)(zws + (size_t)p1c*32);
    float4 a0 = za[0], a1 = za[1], a2 = za[2], a3 = za[3];
    float4 a4 = za[4], a5 = za[5], a6 = za[6], a7 = za[7];
    float4 b0 = zb[0], b1 = zb[1], b2 = zb[2], b3 = zb[3];
    float4 b4 = zb[4], b5 = zb[5], b6 = zb[6], b7 = zb[7];
    float zsq0 = np_pw32(v4sq(a0),v4sq(a1),v4sq(a2),v4sq(a3),
                         v4sq(a4),v4sq(a5),v4sq(a6),v4sq(a7));
    float zsq1 = np_pw32(v4sq(b0),v4sq(b1),v4sq(b2),v4sq(b3),
                         v4sq(b4),v4sq(b5),v4sq(b6),v4sq(b7));

    const int jchunk = cb * CB;
    for (int t = tid; t < CB; t += 256) esq_l[t] = esq[jchunk + t];

    const int tsz   = (CB < 64) ? CB : 64;   // codes per tile
    const int ntile = CB / tsz;
    const int wsl   = tsz >> 2;              // codes per wave per tile
    const int nf4   = tsz << 3;              // float4s per tile

    // stage tile 0
    {
        const float4* g = (const float4*)(emb + (size_t)jchunk*32);
        for (int t = tid; t < nf4; t += 256) ((float4*)ebuf[0])[t] = g[t];
    }
    __syncthreads();

    float best0 = INFINITY, best1 = INFINITY; int bi0 = 0, bi1 = 0;
    for (int tile = 0; tile < ntile; ++tile) {
        const int cur = tile & 1;
        if (tile + 1 < ntile) {
            const float4* g = (const float4*)(emb + (size_t)(jchunk + (tile+1)*tsz)*32);
            for (int t = tid; t < nf4; t += 256) ((float4*)ebuf[cur ^ 1])[t] = g[t];
        }
        const float* eb = ebuf[cur];
        const int lbase = w * wsl;
        for (int i = 0; i < wsl; ++i) {
            const int lc = lbase + i;
            const float4* e4 = (const float4*)(eb + lc*32);
            float acc0 = 0.f, acc1 = 0.f;
            DOT4P(e4, 0, a0, b0) DOT4P(e4, 1, a1, b1) DOT4P(e4, 2, a2, b2) DOT4P(e4, 3, a3, b3)
            DOT4P(e4, 4, a4, b4) DOT4P(e4, 5, a5, b5) DOT4P(e4, 6, a6, b6) DOT4P(e4, 7, a7, b7)
            float sqj = esq_l[tile*tsz + lc];
            float d0 = __fsub_rn(__fadd_rn(zsq0, sqj), __fmul_rn(2.0f, acc0));
            float d1 = __fsub_rn(__fadd_rn(zsq1, sqj), __fmul_rn(2.0f, acc1));
            int j = jchunk + tile*tsz + lc;
            if (d0 < best0) { best0 = d0; bi0 = j; }   // per-wave j ascending: first-index
            if (d1 < best1) { best1 = d1; bi1 = j; }
        }
        __syncthreads();
    }
    red_f[w*128 + lane]      = best0;  red_i[w*128 + lane]      = bi0;
    red_f[w*128 + 64 + lane] = best1;  red_i[w*128 + 64 + lane] = bi1;
    __syncthreads();

    if (tid < 128) {
        const int p = (pblk << 7) + tid;
        if (p < N) {
            float bb = INFINITY; int bi = 0x7fffffff;
            #pragma unroll
            for (int ww = 0; ww < 4; ++ww) {     // wave j-ranges interleave: (d,j) lex
                float sc = red_f[ww*128 + tid];
                int   ji = red_i[ww*128 + tid];
                if (sc < bb || (sc == bb && ji < bi)) { bb = sc; bi = ji; }
            }
            psc[(size_t)p*(ncbMask + 1) + cb] = bb;
            pix[(size_t)p*(ncbMask + 1) + cb] = bi;
        }
    }
}

__global__ __launch_bounds__(256) void vq_final(
    const float* __restrict__ emb, const float* __restrict__ fhat,
    const float* __restrict__ psc, const int* __restrict__ pix,
    float* __restrict__ out)
{
    __shared__ int idx_arr[256];
    const int tid = threadIdx.x;
    const int b = blockIdx.x;
    {   // combine last scale (NCB=8) partials, ascending cb = ascending j
        float best = INFINITY; int bi = 0;
        const size_t pb0 = (size_t)((tid << 6) + b) * 8;
        for (int ch = 0; ch < 8; ++ch) {
            float sc = psc[pb0 + ch];
            if (sc < best) { best = sc; bi = pix[pb0 + ch]; }
        }
        idx_arr[tid] = bi;
    }
    __syncthreads();
    // out = f_hat + h9 (channel-major matches out BCHW), coalesced
    for (int o = tid; o < 8192; o += 256) {
        int c = o >> 8, yx = o & 255;
        out[b*8192 + o] = __fadd_rn(fhat[(size_t)b*8192 + o],
                                    emb[(size_t)idx_arr[yx]*32 + c]);
    }
}

extern "C" void kernel_launch(void* const* d_in, const int* in_sizes, int n_in,
                              void* d_out, int out_size, void* d_ws, size_t ws_size,
                              hipStream_t stream) {
    const float* f   = (const float*)d_in[0];
    const float* emb = (const float*)d_in[1];
    float* ws  = (float*)d_ws;
    float* out = (float*)d_out;
    float* esq   = ws + WS_ESQ;
    float* state = ws + WS_STATE;
    float* fhatp = ws + WS_FHAT;
    float* zws   = ws + WS_Z;
    float* psc   = ws + WS_PSC;
    int*   pixp  = (int*)(ws + WS_PIX);
    static const int pns[10]  = {1, 2, 3, 4, 5, 6, 8, 10, 13, 16};
    static const int ncbl[10] = {7, 7, 6, 6, 5, 5, 4, 4, 3, 3};   // log2(NCB)

    for (int s = 0; s < 10; ++s) {
        int pn = pns[s], V = pn*pn, sh = ncbl[s];
        int PB = ((V << 6) + 127) >> 7;
        vq_apply<<<(s == 0) ? 528 : 512, 256, 0, stream>>>(
            f, emb, esq, state, fhatp, zws, psc, pixp,
            s, pn, s > 0 ? pns[s-1] : 0, s > 0 ? (1 << ncbl[s-1]) : 0);
        vq_scan<<<PB << sh, 256, 0, stream>>>(emb, esq, zws, psc, pixp,
                                              V, (1 << sh) - 1, sh, 4096 >> sh);
    }
    vq_final<<<64, 256, 0, stream>>>(emb, fhatp, psc, pixp, out);
}